// Round 2
// baseline (785.821 us; speedup 1.0000x reference)
//
#include <hip/hip_runtime.h>
#include <hip/hip_bf16.h>

// Problem constants
#define B_   2
#define C_   64
#define H_   96
#define W_   192
#define D_   48
#define G_   8
#define OUT_ 32
#define HW_  (H_ * W_)   // 18432

// Padded f16 correlation volume: (B, DP, HP, WP, 8) halfs, halo = 4
#define DP_ 56
#define HP_ 104
#define WP_ 200
#define PLANE_ (HP_ * WP_ * 8)          // halfs per d-plane = 166400
#define BASEH_HALFS (B_ * DP_ * PLANE_) // 18,636,800 halfs = 37.27 MB

// Workspace layout (float offsets)
#define OFF_FLN   0                        // (B,G,H,W,8) fp32       2,359,296
#define OFF_FRN   2359296                  // (B,G,H,W,8) fp32       2,359,296
#define OFF_BASEH 4718592                  // f16 padded volume      9,318,400 float-slots
#define OFF_SW    14036992                 // (3,B*HW) fp32            110,592
#define OFF_BPACK 14147584                 // f16 B-frags               10,752 float-slots
#define OFF_WP1T  14158336                 // (65,9,32) fp32            18,720
// end = 14,177,056 floats = 56.7 MB

typedef _Float16 f16x8 __attribute__((ext_vector_type(8)));
typedef float    f32x4 __attribute__((ext_vector_type(4)));

// ---------------------------------------------------------------------------
// Kernel 0: weight prep.
//  part A: bpack[k][c][nb][lane][j] = f16( V_k[kk][n] ),
//          kk = c*32 + (lane>>4)*8 + j, n = nb*16 + (lane&15),
//          V_k[tap*8+gi][o] = sum_g wf[o*8+g] * w_k[(g*8+gi)*27+tap], 0 for tap>=27
//  part B: wp1T[ic][t][oc] = w_pred1[oc][ic][t]
// ---------------------------------------------------------------------------
__global__ void wtrans_kernel(const float* __restrict__ w_s,
                              const float* __restrict__ w_m,
                              const float* __restrict__ w_l,
                              const float* __restrict__ w_final,
                              const float* __restrict__ w_pred1,
                              _Float16* __restrict__ bpack,
                              float* __restrict__ wp1T) {
    int i = blockIdx.x * 256 + threadIdx.x;
    if (i < 21504) {
        int j = i & 7;
        int rest = i >> 3;
        int lane = rest & 63;
        int rest2 = rest >> 6;
        int nb = rest2 & 1;
        int rest3 = rest2 >> 1;        // 0..20 = k*7+c
        int c = rest3 % 7;
        int k = rest3 / 7;
        int kk = c * 32 + (lane >> 4) * 8 + j;
        int n  = nb * 16 + (lane & 15);
        int tap = kk >> 3;
        int gi  = kk & 7;
        float val = 0.f;
        if (tap < 27) {
            const float* wsel = (k == 0) ? w_s : (k == 1) ? w_m : w_l;
            #pragma unroll
            for (int g = 0; g < 8; ++g)
                val += w_final[n * 8 + g] * wsel[(g * 8 + gi) * 27 + tap];
        }
        bpack[i] = (_Float16)val;
    } else if (i < 21504 + 18720) {
        int j = i - 21504;
        int oc = j & 31; int it = j >> 5; int ic = it / 9; int t = it - ic * 9;
        wp1T[j] = w_pred1[(oc * 65 + ic) * 9 + t];
    }
}

// ---------------------------------------------------------------------------
// Kernel 1: group-L2-normalize + transpose to channel-last (B,G,H,W,8)
// ---------------------------------------------------------------------------
__global__ __launch_bounds__(256) void norm_kernel(const float* __restrict__ feat_l,
                                                   const float* __restrict__ feat_r,
                                                   float* __restrict__ fln,
                                                   float* __restrict__ frn) {
    int hw = blockIdx.x * 256 + threadIdx.x;
    int bg = blockIdx.y;
    const float* src = blockIdx.z ? feat_r : feat_l;
    float*       dst = blockIdx.z ? frn    : fln;
    float v[8]; float s = 0.f;
    #pragma unroll
    for (int c = 0; c < 8; ++c) {
        v[c] = src[(bg * 8 + c) * HW_ + hw];
        s += v[c] * v[c];
    }
    float inv = 1.0f / fmaxf(sqrtf(s), 1e-12f);
    #pragma unroll
    for (int c = 0; c < 8; ++c) dst[((long)bg * HW_ + hw) * 8 + c] = v[c] * inv;
}

// ---------------------------------------------------------------------------
// Kernel 2: correlation volume -> padded f16 channel-last volume
//  baseh[b][4+d][4+h][4+w][g] = f16( inv * <fl(b,g,h,w,:), fr(b,g,h,w-d,:)> )
// block = 256 = (g 0..7) x (wi 0..31); grid = (W/32, H, B)
// ---------------------------------------------------------------------------
__global__ __launch_bounds__(256) void corr_kernel(const float* __restrict__ fln,
                                                   const float* __restrict__ frn,
                                                   _Float16* __restrict__ baseh) {
    int tid = threadIdx.x;
    int g = tid & 7, wi = tid >> 3;
    int w = blockIdx.x * 32 + wi;
    int h = blockIdx.y;
    int b = blockIdx.z;
    const float* flp  = fln + (size_t)((((b * G_ + g) * H_ + h) * W_ + w)) * 8;
    const float* frow = frn + (size_t)((((b * G_ + g) * H_ + h) * W_)) * 8;
    f32x4 a0 = *(const f32x4*)(flp);
    f32x4 a1 = *(const f32x4*)(flp + 4);
    const float inv = 0.35355339059327373f;  // 1/sqrt(8)
    _Float16* dst = baseh + (size_t)((b * DP_ + 4) * HP_ + 4 + h) * WP_ * 8 + (size_t)(4 + w) * 8 + g;
    for (int d = 0; d < D_; ++d) {
        int wd = w - d;
        float acc = 0.f;
        if (wd >= 0) {
            f32x4 b0 = *(const f32x4*)(frow + wd * 8);
            f32x4 b1 = *(const f32x4*)(frow + wd * 8 + 4);
            acc = a0[0]*b0[0] + a0[1]*b0[1] + a0[2]*b0[2] + a0[3]*b0[3]
                + a1[0]*b1[0] + a1[1]*b1[1] + a1[2]*b1[2] + a1[3]*b1[3];
            acc *= inv;
        }
        dst[(size_t)d * PLANE_] = (_Float16)acc;
    }
}

// ---------------------------------------------------------------------------
// Kernel 3: 2D conv(65->32,3x3)+BN+relu+1x1(32->3)+softmax -> 3 planes swp[k]
// ---------------------------------------------------------------------------
__global__ __launch_bounds__(256) void pred_kernel(const float* __restrict__ feat_l,
                                                   const float* __restrict__ edge,
                                                   const float* __restrict__ wp1T,
                                                   const float* __restrict__ gamma,
                                                   const float* __restrict__ beta,
                                                   const float* __restrict__ mean,
                                                   const float* __restrict__ var,
                                                   const float* __restrict__ w2,
                                                   const float* __restrict__ b2,
                                                   const float* __restrict__ temp,
                                                   float* __restrict__ swp) {
    int pid = blockIdx.x * 256 + threadIdx.x;   // 0..36863
    int b = pid / HW_; int hw = pid - b * HW_;
    int h = hw / W_;   int w = hw - h * W_;

    float acc[32];
    #pragma unroll
    for (int i = 0; i < 32; ++i) acc[i] = 0.f;

    for (int ic = 0; ic < 65; ++ic) {
        const float* src = (ic < 64) ? (feat_l + (size_t)(b * 64 + ic) * HW_)
                                     : (edge + (size_t)b * HW_);
        float v[9];
        #pragma unroll
        for (int ky = 0; ky < 3; ++ky) {
            int y = h + ky - 1;
            #pragma unroll
            for (int kx = 0; kx < 3; ++kx) {
                int x = w + kx - 1;
                bool ok = (y >= 0) && (y < H_) && (x >= 0) && (x < W_);
                v[ky * 3 + kx] = ok ? src[y * W_ + x] : 0.f;
            }
        }
        #pragma unroll
        for (int t = 0; t < 9; ++t) {
            const float* wrow = wp1T + (ic * 9 + t) * 32;
            float vv = v[t];
            #pragma unroll
            for (int oc = 0; oc < 32; ++oc) acc[oc] = fmaf(vv, wrow[oc], acc[oc]);
        }
    }

    float l0 = b2[0], l1 = b2[1], l2 = b2[2];
    #pragma unroll
    for (int oc = 0; oc < 32; ++oc) {
        float sc = gamma[oc] / sqrtf(var[oc] + 1e-5f);
        float xb = (acc[oc] - mean[oc]) * sc + beta[oc];
        float r = fmaxf(xb, 0.f);
        l0 = fmaf(w2[0 * 32 + oc], r, l0);
        l1 = fmaf(w2[1 * 32 + oc], r, l1);
        l2 = fmaf(w2[2 * 32 + oc], r, l2);
    }
    float t = fmaxf(temp[0], 0.1f);
    float it = 1.0f / t;
    l0 *= it; l1 *= it; l2 *= it;
    float m = fmaxf(l0, fmaxf(l1, l2));
    float e0 = __expf(l0 - m), e1 = __expf(l1 - m), e2 = __expf(l2 - m);
    float is = 1.0f / (e0 + e1 + e2);
    swp[0 * (B_ * HW_) + pid] = e0 * is;
    swp[1 * (B_ * HW_) + pid] = e1 * is;
    swp[2 * (B_ * HW_) + pid] = e2 * is;
}

// ---------------------------------------------------------------------------
// Kernel 4: MFMA fused conv.
//  Per scale k: conv_k[pos, o] = sum_{K=216} A[pos,K] * V_k[K,o]  (f16 MFMA)
//  out[pos,o] = bf[o] + sum_k swp[k][pos] * conv_k[pos,o]
//  Wave: M = 16 consecutive w at fixed (b,h); loops 24 d values.
//  mfma_f32_16x16x32_f16: A[m=lane&15][k=(lane>>4)*8+j], B[k][n=lane&15],
//  D[row=(lane>>4)*4+i][col=lane&15]  (row = w-offset, col = o)
// block = 256 = 4 waves (w-tiles); grid = (3, H, B*2 d-halves)
// ---------------------------------------------------------------------------
__global__ __launch_bounds__(256, 2) void fusedconv_mfma(
        const _Float16* __restrict__ baseh,
        const float* __restrict__ swp,
        const _Float16* __restrict__ bpack,
        const float* __restrict__ bf,
        float* __restrict__ out) {
    int tid = threadIdx.x;
    int wave = tid >> 6, lane = tid & 63;
    int m = lane & 15, quad = lane >> 4;
    int wt = blockIdx.x * 4 + wave;          // 0..11
    int w0 = wt * 16;
    int h  = blockIdx.y;
    int bz = blockIdx.z;                     // b*2 + dhalf
    int b  = bz >> 1;
    int d0 = (bz & 1) * 24;

    // B fragments: 3 scales x 7 K-chunks x 2 n-blocks, resident for the d-loop
    f16x8 Bf[3][7][2];
    #pragma unroll
    for (int k = 0; k < 3; ++k)
        #pragma unroll
        for (int c = 0; c < 7; ++c)
            #pragma unroll
            for (int nb = 0; nb < 2; ++nb)
                Bf[k][c][nb] = *(const f16x8*)(bpack + ((((k * 7 + c) * 2 + nb) * 64 + lane) * 8));

    // softmax weights: rows quad*4..+3 (w-offsets), independent of d
    f32x4 swv[3];
    #pragma unroll
    for (int k = 0; k < 3; ++k)
        swv[k] = *(const f32x4*)(swp + k * (B_ * HW_) + b * HW_ + h * W_ + w0 + quad * 4);

    // per-lane A offsets (halfs) relative to the (d, h, w0) interior origin
    int aoff[3][7];
    #pragma unroll
    for (int k = 0; k < 3; ++k) {
        int dil = 1 << k;
        #pragma unroll
        for (int c = 0; c < 7; ++c) {
            int tap = c * 4 + quad;
            if (tap > 26) tap = 13;   // (0,0,0) offset; its B column is zero
            int kd = tap / 9 - 1; int r = tap % 9;
            int kh = r / 3 - 1;   int kw = r % 3 - 1;
            aoff[k][c] = ((kd * dil) * HP_ + kh * dil) * (WP_ * 8) + (kw * dil + m) * 8;
        }
    }

    const _Float16* p0 = baseh + (size_t)(((b * DP_ + 4 + d0) * HP_ + 4 + h) * WP_ + 4 + w0) * 8;
    float bias0 = bf[m], bias1 = bf[m + 16];
    float* outp = out + (size_t)(b * OUT_) * (D_ * HW_) + h * W_ + w0 + quad * 4;

    for (int d = 0; d < 24; ++d) {
        const _Float16* pd = p0 + (size_t)d * PLANE_;
        f32x4 fused0 = {0.f, 0.f, 0.f, 0.f}, fused1 = {0.f, 0.f, 0.f, 0.f};
        #pragma unroll
        for (int k = 0; k < 3; ++k) {
            f32x4 acc0 = {0.f, 0.f, 0.f, 0.f}, acc1 = {0.f, 0.f, 0.f, 0.f};
            #pragma unroll
            for (int c = 0; c < 7; ++c) {
                f16x8 a = *(const f16x8*)(pd + aoff[k][c]);
                acc0 = __builtin_amdgcn_mfma_f32_16x16x32_f16(a, Bf[k][c][0], acc0, 0, 0, 0);
                acc1 = __builtin_amdgcn_mfma_f32_16x16x32_f16(a, Bf[k][c][1], acc1, 0, 0, 0);
            }
            #pragma unroll
            for (int i = 0; i < 4; ++i) {
                fused0[i] += swv[k][i] * acc0[i];
                fused1[i] += swv[k][i] * acc1[i];
            }
        }
        f32x4 s0, s1;
        #pragma unroll
        for (int i = 0; i < 4; ++i) { s0[i] = fused0[i] + bias0; s1[i] = fused1[i] + bias1; }
        int dd = d0 + d;
        *(f32x4*)(outp + (size_t)(m * D_ + dd) * HW_)        = s0;   // o = m
        *(f32x4*)(outp + (size_t)((m + 16) * D_ + dd) * HW_) = s1;   // o = m+16
    }
}

// ---------------------------------------------------------------------------
extern "C" void kernel_launch(void* const* d_in, const int* in_sizes, int n_in,
                              void* d_out, int out_size, void* d_ws, size_t ws_size,
                              hipStream_t stream) {
    const float* feat_l   = (const float*)d_in[0];
    const float* feat_r   = (const float*)d_in[1];
    const float* edge     = (const float*)d_in[2];
    const float* w_pred1  = (const float*)d_in[3];
    const float* bn_gamma = (const float*)d_in[4];
    const float* bn_beta  = (const float*)d_in[5];
    const float* bn_mean  = (const float*)d_in[6];
    const float* bn_var   = (const float*)d_in[7];
    const float* w_pred2  = (const float*)d_in[8];
    const float* b_pred2  = (const float*)d_in[9];
    const float* temp     = (const float*)d_in[10];
    const float* w_s      = (const float*)d_in[11];
    const float* w_m      = (const float*)d_in[12];
    const float* w_l      = (const float*)d_in[13];
    const float* w_final  = (const float*)d_in[14];
    const float* b_final  = (const float*)d_in[15];
    float* out = (float*)d_out;

    float* ws = (float*)d_ws;
    float*     fln   = ws + OFF_FLN;
    float*     frn   = ws + OFF_FRN;
    _Float16*  baseh = (_Float16*)(ws + OFF_BASEH);
    float*     swp   = ws + OFF_SW;
    _Float16*  bpack = (_Float16*)(ws + OFF_BPACK);
    float*     wp1T  = ws + OFF_WP1T;

    // 0: weight prep
    wtrans_kernel<<<dim3(158), 256, 0, stream>>>(w_s, w_m, w_l, w_final, w_pred1, bpack, wp1T);
    // zero the padded volume (halo must be 0; ws is poisoned each launch)
    hipMemsetAsync(baseh, 0, (size_t)BASEH_HALFS * sizeof(_Float16), stream);
    // 1: normalize
    norm_kernel<<<dim3(HW_ / 256, B_ * G_, 2), 256, 0, stream>>>(feat_l, feat_r, fln, frn);
    // 2: correlation volume -> padded f16
    corr_kernel<<<dim3(W_ / 32, H_, B_), 256, 0, stream>>>(fln, frn, baseh);
    // 3: pred path -> softmax planes
    pred_kernel<<<dim3(B_ * HW_ / 256), 256, 0, stream>>>(feat_l, edge, wp1T, bn_gamma,
                                                          bn_beta, bn_mean, bn_var,
                                                          w_pred2, b_pred2, temp, swp);
    // 4: MFMA fused conv
    fusedconv_mfma<<<dim3(3, H_, B_ * 2), 256, 0, stream>>>(baseh, swp, bpack, b_final, out);
}

// Round 3
// 681.391 us; speedup vs baseline: 1.1533x; 1.1533x over previous
//
#include <hip/hip_runtime.h>
#include <hip/hip_bf16.h>

// Problem constants
#define B_   2
#define C_   64
#define H_   96
#define W_   192
#define D_   48
#define G_   8
#define OUT_ 32
#define HW_  (H_ * W_)   // 18432

// Padded f16 correlation volume: (B, DP, HP, WP, 8) halfs, halo = 4
#define DP_ 56
#define HP_ 104
#define WP_ 200
#define PLANE_ (HP_ * WP_ * 8)          // halfs per d-plane = 166400
#define BASEH_HALFS (B_ * DP_ * PLANE_) // 18,636,800 halfs = 37.27 MB

// Workspace layout (float offsets)
#define OFF_FLN   0                        // (B,G,H,W,8) fp32       2,359,296
#define OFF_FRN   2359296                  // (B,G,H,W,8) fp32       2,359,296
#define OFF_BASEH 4718592                  // f16 padded volume      9,318,400 float-slots
#define OFF_SW    14036992                 // (3,B*HW) fp32            110,592
#define OFF_BPACK 14147584                 // f16 B-frags               10,752 float-slots
#define OFF_WP1T  14158336                 // (65,9,32) fp32            18,720

typedef _Float16 f16x8  __attribute__((ext_vector_type(8)));
typedef float    f32x4  __attribute__((ext_vector_type(4)));
typedef float    f32x16 __attribute__((ext_vector_type(16)));

// ---------------------------------------------------------------------------
// Kernel 0: weight prep for 32x32x16 MFMA.
//  bpack[((k*14+c)*64+lane)*8+j] = f16( V_k[tap(c,hf)][gi=j][n=lane&31] )
//  hf = lane>>5. Chunk->tap mapping (must match fused kernel's addressing):
//   c in [0,9):  kd = hf? +1 : -1 ; kh = c/3-1 ; kw = c%3-1
//   c in [9,12): kd = 0 ; kh = hf? +1 : -1 ; kw = (c-9)-1
//   c == 12:     kd = 0 ; kh = 0 ; kw = hf? +1 : -1
//   c == 13:     hf==0 -> center (0,0,0) ; hf==1 -> zero pad
//  V_k[tap][gi][n] = sum_g w_final[n*8+g] * w_k[(g*8+gi)*27+tap]
//  part B: wp1T[ic][t][oc] = w_pred1[oc][ic][t]
// ---------------------------------------------------------------------------
__global__ void wtrans_kernel(const float* __restrict__ w_s,
                              const float* __restrict__ w_m,
                              const float* __restrict__ w_l,
                              const float* __restrict__ w_final,
                              const float* __restrict__ w_pred1,
                              _Float16* __restrict__ bpack,
                              float* __restrict__ wp1T) {
    int i = blockIdx.x * 256 + threadIdx.x;
    if (i < 21504) {
        int j = i & 7;                 // gi
        int lane = (i >> 3) & 63;
        int kc = i >> 9;               // 0..41
        int c = kc % 14, k = kc / 14;
        int hf = lane >> 5, n = lane & 31;
        int kd = 0, kh = 0, kw = 0; bool valid = true;
        if (c < 9)        { kd = hf ? 1 : -1; kh = c / 3 - 1; kw = c % 3 - 1; }
        else if (c < 12)  { kd = 0; kh = hf ? 1 : -1; kw = (c - 9) - 1; }
        else if (c == 12) { kd = 0; kh = 0; kw = hf ? 1 : -1; }
        else              { valid = (hf == 0); }
        float val = 0.f;
        if (valid) {
            int tap = (kd + 1) * 9 + (kh + 1) * 3 + (kw + 1);
            const float* wsel = (k == 0) ? w_s : (k == 1) ? w_m : w_l;
            #pragma unroll
            for (int g = 0; g < 8; ++g)
                val += w_final[n * 8 + g] * wsel[(g * 8 + j) * 27 + tap];
        }
        bpack[i] = (_Float16)val;
    } else if (i < 21504 + 18720) {
        int j = i - 21504;
        int oc = j & 31; int it = j >> 5; int ic = it / 9; int t = it - ic * 9;
        wp1T[j] = w_pred1[(oc * 65 + ic) * 9 + t];
    }
}

// ---------------------------------------------------------------------------
// Kernel 1: group-L2-normalize + transpose to channel-last (B,G,H,W,8)
// ---------------------------------------------------------------------------
__global__ __launch_bounds__(256) void norm_kernel(const float* __restrict__ feat_l,
                                                   const float* __restrict__ feat_r,
                                                   float* __restrict__ fln,
                                                   float* __restrict__ frn) {
    int hw = blockIdx.x * 256 + threadIdx.x;
    int bg = blockIdx.y;
    const float* src = blockIdx.z ? feat_r : feat_l;
    float*       dst = blockIdx.z ? frn    : fln;
    float v[8]; float s = 0.f;
    #pragma unroll
    for (int c = 0; c < 8; ++c) {
        v[c] = src[(bg * 8 + c) * HW_ + hw];
        s += v[c] * v[c];
    }
    float inv = 1.0f / fmaxf(sqrtf(s), 1e-12f);
    #pragma unroll
    for (int c = 0; c < 8; ++c) dst[((long)bg * HW_ + hw) * 8 + c] = v[c] * inv;
}

// ---------------------------------------------------------------------------
// Kernel 2: correlation volume -> padded f16 channel-last volume
// ---------------------------------------------------------------------------
__global__ __launch_bounds__(256) void corr_kernel(const float* __restrict__ fln,
                                                   const float* __restrict__ frn,
                                                   _Float16* __restrict__ baseh) {
    int tid = threadIdx.x;
    int g = tid & 7, wi = tid >> 3;
    int w = blockIdx.x * 32 + wi;
    int h = blockIdx.y;
    int b = blockIdx.z;
    const float* flp  = fln + (size_t)((((b * G_ + g) * H_ + h) * W_ + w)) * 8;
    const float* frow = frn + (size_t)((((b * G_ + g) * H_ + h) * W_)) * 8;
    f32x4 a0 = *(const f32x4*)(flp);
    f32x4 a1 = *(const f32x4*)(flp + 4);
    const float inv = 0.35355339059327373f;  // 1/sqrt(8)
    _Float16* dst = baseh + (size_t)((b * DP_ + 4) * HP_ + 4 + h) * WP_ * 8 + (size_t)(4 + w) * 8 + g;
    for (int d = 0; d < D_; ++d) {
        int wd = w - d;
        float acc = 0.f;
        if (wd >= 0) {
            f32x4 b0 = *(const f32x4*)(frow + wd * 8);
            f32x4 b1 = *(const f32x4*)(frow + wd * 8 + 4);
            acc = a0[0]*b0[0] + a0[1]*b0[1] + a0[2]*b0[2] + a0[3]*b0[3]
                + a1[0]*b1[0] + a1[1]*b1[1] + a1[2]*b1[2] + a1[3]*b1[3];
            acc *= inv;
        }
        dst[(size_t)d * PLANE_] = (_Float16)acc;
    }
}

// ---------------------------------------------------------------------------
// Kernel 3: 2D conv(65->32,3x3)+BN+relu+1x1(32->3)+softmax -> 3 planes swp[k]
// ---------------------------------------------------------------------------
__global__ __launch_bounds__(256) void pred_kernel(const float* __restrict__ feat_l,
                                                   const float* __restrict__ edge,
                                                   const float* __restrict__ wp1T,
                                                   const float* __restrict__ gamma,
                                                   const float* __restrict__ beta,
                                                   const float* __restrict__ mean,
                                                   const float* __restrict__ var,
                                                   const float* __restrict__ w2,
                                                   const float* __restrict__ b2,
                                                   const float* __restrict__ temp,
                                                   float* __restrict__ swp) {
    int pid = blockIdx.x * 256 + threadIdx.x;   // 0..36863
    int b = pid / HW_; int hw = pid - b * HW_;
    int h = hw / W_;   int w = hw - h * W_;

    float acc[32];
    #pragma unroll
    for (int i = 0; i < 32; ++i) acc[i] = 0.f;

    for (int ic = 0; ic < 65; ++ic) {
        const float* src = (ic < 64) ? (feat_l + (size_t)(b * 64 + ic) * HW_)
                                     : (edge + (size_t)b * HW_);
        float v[9];
        #pragma unroll
        for (int ky = 0; ky < 3; ++ky) {
            int y = h + ky - 1;
            #pragma unroll
            for (int kx = 0; kx < 3; ++kx) {
                int x = w + kx - 1;
                bool ok = (y >= 0) && (y < H_) && (x >= 0) && (x < W_);
                v[ky * 3 + kx] = ok ? src[y * W_ + x] : 0.f;
            }
        }
        #pragma unroll
        for (int t = 0; t < 9; ++t) {
            const float* wrow = wp1T + (ic * 9 + t) * 32;
            float vv = v[t];
            #pragma unroll
            for (int oc = 0; oc < 32; ++oc) acc[oc] = fmaf(vv, wrow[oc], acc[oc]);
        }
    }

    float l0 = b2[0], l1 = b2[1], l2 = b2[2];
    #pragma unroll
    for (int oc = 0; oc < 32; ++oc) {
        float sc = gamma[oc] / sqrtf(var[oc] + 1e-5f);
        float xb = (acc[oc] - mean[oc]) * sc + beta[oc];
        float r = fmaxf(xb, 0.f);
        l0 = fmaf(w2[0 * 32 + oc], r, l0);
        l1 = fmaf(w2[1 * 32 + oc], r, l1);
        l2 = fmaf(w2[2 * 32 + oc], r, l2);
    }
    float t = fmaxf(temp[0], 0.1f);
    float it = 1.0f / t;
    l0 *= it; l1 *= it; l2 *= it;
    float m = fmaxf(l0, fmaxf(l1, l2));
    float e0 = __expf(l0 - m), e1 = __expf(l1 - m), e2 = __expf(l2 - m);
    float is = 1.0f / (e0 + e1 + e2);
    swp[0 * (B_ * HW_) + pid] = e0 * is;
    swp[1 * (B_ * HW_) + pid] = e1 * is;
    swp[2 * (B_ * HW_) + pid] = e2 * is;
}

// ---------------------------------------------------------------------------
// Kernel 4: MFMA 32x32x16 fused conv.
//  Wave = 32 consecutive w at fixed (b,h), sweeping 24 d values.
//  A[m=lane&31][kk=(lane>>5)*8+j]: lane loads 8 gi-halfs of tap T(c,hf) at
//  row w0+m. softmax weight sw_k(h, w0+m) is folded into A (f16 mul), so a
//  single accumulator chain (split in 2 for MFMA latency) covers all scales.
//  D: col = lane&31 = o, row = (reg&3)+8*(reg>>2)+4*hf = w-offset.
// block 256 = 4 waves = (2 h) x (2 d-halves); grid = (6 wtiles, 48, B)
// ---------------------------------------------------------------------------
__global__ __launch_bounds__(256, 2) void fusedconv_mfma32(
        const _Float16* __restrict__ baseh,
        const float* __restrict__ swp,
        const _Float16* __restrict__ bpack,
        const float* __restrict__ bf,
        float* __restrict__ out) {
    int tid = threadIdx.x;
    int wave = tid >> 6, lane = tid & 63;
    int m = lane & 31, hf = lane >> 5;
    int hh = wave >> 1, dh = wave & 1;
    int w0 = blockIdx.x * 32;
    int h  = blockIdx.y * 2 + hh;
    int b  = blockIdx.z;
    int d0 = dh * 24;

    // resident B fragments: 3 scales x 14 K-chunks
    f16x8 Bf[3][14];
    #pragma unroll
    for (int k = 0; k < 3; ++k)
        #pragma unroll
        for (int c = 0; c < 14; ++c)
            Bf[k][c] = *(const f16x8*)(bpack + ((k * 14 + c) * 64 + lane) * 8);

    // softmax weights as f16 splats (per-lane row m)
    f16x8 swh[3];
    #pragma unroll
    for (int k = 0; k < 3; ++k) {
        float s = swp[k * (B_ * HW_) + b * HW_ + h * W_ + w0 + m];
        _Float16 hs = (_Float16)s;
        f16x8 t;
        #pragma unroll
        for (int j = 0; j < 8; ++j) t[j] = hs;
        swh[k] = t;
    }

    // half-wave address deltas per (scale, class), bytes
    int hdv[3][4];
    #pragma unroll
    for (int k = 0; k < 3; ++k) {
        int dil = 1 << k;
        hdv[k][0] = hf * (2 * dil * HP_ * WP_ * 8 * 2);
        hdv[k][1] = hf * (2 * dil * WP_ * 8 * 2);
        hdv[k][2] = hf * (2 * dil * 8 * 2);
        hdv[k][3] = 0;
    }

    const char* bb = (const char*)baseh;
    char*       ob = (char*)out;

    // byte offset of interior origin (d0-plane, h, w0+m)
    unsigned pm = (unsigned)(((((b * DP_ + 4 + d0) * HP_ + 4 + h) * WP_ + 4 + w0 + m) * 8) * 2);
    float bias = bf[m];   // o = lane&31
    unsigned outoff = (unsigned)((((b * OUT_ + m) * D_ + d0) * HW_ + h * W_ + w0 + 4 * hf) * 4);

    for (int d = 0; d < 24; ++d) {
        f32x16 acc0 = {0.f}, acc1 = {0.f};
        #pragma unroll
        for (int i = 0; i < 16; ++i) { acc0[i] = 0.f; acc1[i] = 0.f; }
        #pragma unroll
        for (int k = 0; k < 3; ++k) {
            int dil = 1 << k;
            #pragma unroll
            for (int c = 0; c < 14; ++c) {
                int coff, cls;
                if (c < 9)        { coff = ((-dil * HP_ + (c / 3 - 1) * dil) * WP_ * 8 + (c % 3 - 1) * dil * 8) * 2; cls = 0; }
                else if (c < 12)  { coff = ((-dil) * WP_ * 8 + ((c - 9) - 1) * dil * 8) * 2;                          cls = 1; }
                else if (c == 12) { coff = -dil * 16;                                                                  cls = 2; }
                else              { coff = 0;                                                                          cls = 3; }
                unsigned a = pm + (unsigned)(hdv[k][cls] + coff);
                f16x8 av = *(const f16x8*)(bb + a);
                av = av * swh[k];
                if (c & 1) acc1 = __builtin_amdgcn_mfma_f32_32x32x16_f16(av, Bf[k][c], acc1, 0, 0, 0);
                else       acc0 = __builtin_amdgcn_mfma_f32_32x32x16_f16(av, Bf[k][c], acc0, 0, 0, 0);
            }
        }
        #pragma unroll
        for (int q = 0; q < 4; ++q) {
            f32x4 v;
            #pragma unroll
            for (int i = 0; i < 4; ++i) v[i] = acc0[4 * q + i] + acc1[4 * q + i] + bias;
            *(f32x4*)(ob + outoff + q * 32) = v;   // rows 8q+4hf..+3, o = m
        }
        pm += PLANE_ * 2;
        outoff += HW_ * 4;
    }
}

// ---------------------------------------------------------------------------
extern "C" void kernel_launch(void* const* d_in, const int* in_sizes, int n_in,
                              void* d_out, int out_size, void* d_ws, size_t ws_size,
                              hipStream_t stream) {
    const float* feat_l   = (const float*)d_in[0];
    const float* feat_r   = (const float*)d_in[1];
    const float* edge     = (const float*)d_in[2];
    const float* w_pred1  = (const float*)d_in[3];
    const float* bn_gamma = (const float*)d_in[4];
    const float* bn_beta  = (const float*)d_in[5];
    const float* bn_mean  = (const float*)d_in[6];
    const float* bn_var   = (const float*)d_in[7];
    const float* w_pred2  = (const float*)d_in[8];
    const float* b_pred2  = (const float*)d_in[9];
    const float* temp     = (const float*)d_in[10];
    const float* w_s      = (const float*)d_in[11];
    const float* w_m      = (const float*)d_in[12];
    const float* w_l      = (const float*)d_in[13];
    const float* w_final  = (const float*)d_in[14];
    const float* b_final  = (const float*)d_in[15];
    float* out = (float*)d_out;

    float* ws = (float*)d_ws;
    float*     fln   = ws + OFF_FLN;
    float*     frn   = ws + OFF_FRN;
    _Float16*  baseh = (_Float16*)(ws + OFF_BASEH);
    float*     swp   = ws + OFF_SW;
    _Float16*  bpack = (_Float16*)(ws + OFF_BPACK);
    float*     wp1T  = ws + OFF_WP1T;

    // 0: weight prep
    wtrans_kernel<<<dim3(158), 256, 0, stream>>>(w_s, w_m, w_l, w_final, w_pred1, bpack, wp1T);
    // zero the padded volume (halo must be 0; ws is poisoned each launch)
    hipMemsetAsync(baseh, 0, (size_t)BASEH_HALFS * sizeof(_Float16), stream);
    // 1: normalize
    norm_kernel<<<dim3(HW_ / 256, B_ * G_, 2), 256, 0, stream>>>(feat_l, feat_r, fln, frn);
    // 2: correlation volume -> padded f16
    corr_kernel<<<dim3(W_ / 32, H_, B_), 256, 0, stream>>>(fln, frn, baseh);
    // 3: pred path -> softmax planes
    pred_kernel<<<dim3(B_ * HW_ / 256), 256, 0, stream>>>(feat_l, edge, wp1T, bn_gamma,
                                                          bn_beta, bn_mean, bn_var,
                                                          w_pred2, b_pred2, temp, swp);
    // 4: MFMA 32x32 fused conv
    fusedconv_mfma32<<<dim3(W_ / 32, H_ / 2, B_), 256, 0, stream>>>(baseh, swp, bpack, b_final, out);
}